// Round 1
// baseline (600.370 us; speedup 1.0000x reference)
//
#include <hip/hip_runtime.h>
#include <stdint.h>

// TBN BasicBlock on MI355X:
//   out = x + conv3x3(sign(bn2(conv3x3(sign(bn1(x)), tern(w1)))), tern(w2))
// Binary acts (+-1) and ternary weights ({-1,0,+1}, alpha factored out) are
// exact in bf16, so both convs run as implicit-GEMM bf16 MFMA with fp32
// accumulation (integer-exact), alpha applied in the epilogue.
//
// Workspace layout (needs ~70 MB):
//   [0,32MB)      a1  : binarized bn1(x), NHWC bf16-bits
//   [32,64MB)     a2  : binarized bn2(conv1), NHWC bf16-bits
//   [64MB..)      wqt1, wqt2 : ternary weights as bf16 bits, [co][tap*256+ci]
//   then small float scratch (partials, delta, alpha, bn2 affine).

#define EPS 1e-5f

typedef __bf16 bf16x8 __attribute__((ext_vector_type(8)));
typedef float  f32x4  __attribute__((ext_vector_type(4)));

// ---------------- stage 1: sum |w| (deterministic 2-level reduction) --------
__global__ __launch_bounds__(256) void wsum_kernel(const float* __restrict__ w,
                                                   float* __restrict__ partial) {
  __shared__ float red[256];
  const int t = threadIdx.x;
  const int b = blockIdx.x;
  float s = 0.f;
#pragma unroll
  for (int i = 0; i < 32; ++i) s += fabsf(w[b * 256 + t + i * 18432]);
  red[t] = s;
  __syncthreads();
  for (int o = 128; o > 0; o >>= 1) {
    if (t < o) red[t] += red[t + o];
    __syncthreads();
  }
  if (t == 0) partial[b] = red[0];
}

__global__ void delta_kernel(const float* __restrict__ p1, const float* __restrict__ p2,
                             float* __restrict__ delta) {
  const int t = threadIdx.x;
  if (t < 2) {
    const float* p = (t == 0) ? p1 : p2;
    double s = 0.0;
    for (int i = 0; i < 72; ++i) s += (double)p[i];
    delta[t] = 0.7f * (float)(s * (1.0 / 589824.0));
  }
}

// ------------- stage 2: quantize + transpose weights, alpha partials --------
__global__ __launch_bounds__(256) void quant_kernel(const float* __restrict__ w,
                                                    const float* __restrict__ delta2, const int didx,
                                                    uint16_t* __restrict__ wqt,
                                                    float* __restrict__ psum,
                                                    float* __restrict__ pcnt) {
  __shared__ float rs[256];
  __shared__ float rc[256];
  const int t = threadIdx.x;
  const int idx = blockIdx.x * 256 + t;
  const float d = delta2[didx];
  const float v = w[idx];
  const float av = fabsf(v);
  const bool m = av > d;
  const int co = idx / 2304;
  const int rem = idx - co * 2304;
  const int ci = rem / 9;
  const int tap = rem - ci * 9;
  // B^T layout: [co][tap*256 + ci], bf16 bit patterns of {-1,0,+1}
  wqt[co * 2304 + tap * 256 + ci] = m ? (v > 0.f ? (uint16_t)0x3F80u : (uint16_t)0xBF80u)
                                      : (uint16_t)0u;
  rs[t] = m ? av : 0.f;
  rc[t] = m ? 1.f : 0.f;
  __syncthreads();
  for (int o = 128; o > 0; o >>= 1) {
    if (t < o) { rs[t] += rs[t + o]; rc[t] += rc[t + o]; }
    __syncthreads();
  }
  if (t == 0) { psum[blockIdx.x] = rs[0]; pcnt[blockIdx.x] = rc[0]; }
}

__global__ __launch_bounds__(256) void alpha_kernel(const float* __restrict__ ps1, const float* __restrict__ pc1,
                                                    const float* __restrict__ ps2, const float* __restrict__ pc2,
                                                    const float* __restrict__ g2, const float* __restrict__ b2,
                                                    const float* __restrict__ m2, const float* __restrict__ v2,
                                                    float* __restrict__ alphas,
                                                    float* __restrict__ inv2o, float* __restrict__ add2o) {
  __shared__ float rs[256];
  __shared__ float rc[256];
  const int t = threadIdx.x;
  float s1 = 0.f, c1 = 0.f, s2 = 0.f, c2 = 0.f;
#pragma unroll
  for (int i = 0; i < 9; ++i) {
    s1 += ps1[t + (i << 8)]; c1 += pc1[t + (i << 8)];
    s2 += ps2[t + (i << 8)]; c2 += pc2[t + (i << 8)];
  }
  rs[t] = s1; rc[t] = c1;
  __syncthreads();
  for (int o = 128; o > 0; o >>= 1) {
    if (t < o) { rs[t] += rs[t + o]; rc[t] += rc[t + o]; }
    __syncthreads();
  }
  if (t == 0) alphas[0] = rs[0] / fmaxf(rc[0], 1.f);
  __syncthreads();
  rs[t] = s2; rc[t] = c2;
  __syncthreads();
  for (int o = 128; o > 0; o >>= 1) {
    if (t < o) { rs[t] += rs[t + o]; rc[t] += rc[t + o]; }
    __syncthreads();
  }
  if (t == 0) alphas[1] = rs[0] / fmaxf(rc[0], 1.f);
  // bn2 affine precompute
  const float inv = g2[t] * rsqrtf(v2[t] + EPS);
  inv2o[t] = inv;
  add2o[t] = b2[t] - m2[t] * inv;
}

// -------- stage 3: bn1 + binarize + NCHW -> NHWC (bf16 +-1 bits) ------------
__global__ __launch_bounds__(256) void bn_bin_kernel(const float* __restrict__ x,
                                                     const float* __restrict__ g1,
                                                     const float* __restrict__ b1,
                                                     const float* __restrict__ m1,
                                                     const float* __restrict__ v1,
                                                     uint16_t* __restrict__ a1) {
  __shared__ uint16_t lds[64 * 36];  // [pixel][channel], stride 36 to dodge conflicts
  const int t = threadIdx.x;
  const int p0 = blockIdx.x << 6;   // 64-pixel group within image
  const int c0 = blockIdx.y << 5;   // 32-channel group
  const int n = blockIdx.z;
  const int pl = t & 63;
  const int cl0 = t >> 6;
#pragma unroll
  for (int i = 0; i < 8; ++i) {
    const int cl = cl0 + (i << 2);
    const int c = c0 + cl;
    const float inv = g1[c] * rsqrtf(v1[c] + EPS);
    const float ad = b1[c] - m1[c] * inv;
    const float val = x[(((n << 8) + c) << 10) + p0 + pl];
    const float tt = fmaf(val, inv, ad);
    lds[pl * 36 + cl] = (tt >= 0.f) ? (uint16_t)0x3F80u : (uint16_t)0xBF80u;
  }
  __syncthreads();
  const int pl2 = t >> 2;
  const int s2 = (t & 3) << 3;
  const uint2 lo = *(const uint2*)&lds[pl2 * 36 + s2];
  const uint2 hi = *(const uint2*)&lds[pl2 * 36 + s2 + 4];
  uint4 o; o.x = lo.x; o.y = lo.y; o.z = hi.x; o.w = hi.y;
  *(uint4*)&a1[(((n << 10) + p0 + pl2) << 8) + c0 + s2] = o;
}

// -------- stages 4/5: implicit-GEMM conv3x3 with fused epilogues ------------
// Tile: BM=128 pixels (4 image rows) x BN=128 cout, 4 waves (2M x 2N),
// K-loop: 4 ci-chunks of 64 x 9 taps. LDS XOR-swizzled (slot ^= row&7).
// A-halo: out-of-image fragments redirected to a zeroed LDS row (192).
template <int EPI>
__global__ __launch_bounds__(256) void conv3x3_tbn(
    const uint16_t* __restrict__ act,   // NHWC bf16-bits [B*1024][256]
    const uint16_t* __restrict__ wqt,   // [256][2304] tap-major
    const float* __restrict__ alphas, const int aidx,
    const float* __restrict__ inv2, const float* __restrict__ add2,  // EPI==0
    const float* __restrict__ xres,                                  // EPI==1
    uint16_t* __restrict__ aout, float* __restrict__ fout) {
  __shared__ uint16_t ldsA[193 * 64];  // 192 pixel rows x 128B + zero row
  __shared__ uint16_t ldsB[128 * 64];  // 128 co rows x 128B
  const char* ldsAc = (const char*)ldsA;
  const char* ldsBc = (const char*)ldsB;

  const int tid = threadIdx.x;
  const int mb = blockIdx.x >> 1;   // 512 pixel tiles
  const int nb = blockIdx.x & 1;    // 2 cout halves
  const int n = mb >> 3;
  const int y0 = (mb & 7) << 2;     // 4 image rows per tile
  const int l = tid & 63;
  const int wid = tid >> 6;
  const int wm = wid >> 1;
  const int wn = wid & 1;
  const int q = l >> 4;
  const int r = l & 15;

  int ylocal[4], xcol[4], coL[4];
#pragma unroll
  for (int mi = 0; mi < 4; ++mi) {
    const int p = wm * 64 + mi * 16 + r;
    ylocal[mi] = p >> 5;
    xcol[mi] = p & 31;
  }
#pragma unroll
  for (int ni = 0; ni < 4; ++ni) coL[ni] = wn * 64 + ni * 16 + r;

  if (tid < 8) *(uint4*)((char*)ldsA + 192 * 128 + tid * 16) = make_uint4(0u, 0u, 0u, 0u);

  const f32x4 fz = {0.f, 0.f, 0.f, 0.f};
  f32x4 acc[4][4];
#pragma unroll
  for (int mi = 0; mi < 4; ++mi)
#pragma unroll
    for (int ni = 0; ni < 4; ++ni) acc[mi][ni] = fz;

  const int actbase = n << 18;   // n*1024*256
  const int wbase = nb << 7;

  for (int chunk = 0; chunk < 4; ++chunk) {
    const int ci0 = chunk << 6;
#pragma unroll
    for (int tap = 0; tap < 9; ++tap) {
      const int ky = tap / 3, kx = tap % 3;
      // issue global->reg loads early (overlap with pre-barrier wait)
      uint4 tA[6];
      if (tap == 0) {
#pragma unroll
        for (int i = 0; i < 6; ++i) {
          const int idx = tid + (i << 8);
          const int pix = idx >> 3, s = idx & 7;
          int ys = y0 - 1 + (pix >> 5);
          ys = ys < 0 ? 0 : (ys > 31 ? 31 : ys);  // clamp for address safety only
          tA[i] = *(const uint4*)(act + actbase + (((ys << 5) + (pix & 31)) << 8) + ci0 + (s << 3));
        }
      }
      uint4 tB[4];
#pragma unroll
      for (int i = 0; i < 4; ++i) {
        const int idx = tid + (i << 8);
        const int co = idx >> 3, s = idx & 7;
        tB[i] = *(const uint4*)(wqt + (wbase + co) * 2304 + tap * 256 + ci0 + (s << 3));
      }
      __syncthreads();  // all waves done reading previous tile
      if (tap == 0) {
#pragma unroll
        for (int i = 0; i < 6; ++i) {
          const int idx = tid + (i << 8);
          const int pix = idx >> 3, s = idx & 7;
          *(uint4*)((char*)ldsA + pix * 128 + ((s ^ (pix & 7)) << 4)) = tA[i];
        }
      }
#pragma unroll
      for (int i = 0; i < 4; ++i) {
        const int idx = tid + (i << 8);
        const int co = idx >> 3, s = idx & 7;
        *(uint4*)((char*)ldsB + co * 128 + ((s ^ (co & 7)) << 4)) = tB[i];
      }
      __syncthreads();  // staged tile visible

      int apix[4];
#pragma unroll
      for (int mi = 0; mi < 4; ++mi) {
        const int xs = xcol[mi] + kx - 1;
        const int ys = y0 + ylocal[mi] + ky - 1;
        const bool valid = ((unsigned)xs < 32u) && ((unsigned)ys < 32u);
        const int pp = ((ylocal[mi] + ky) << 5) + (xs & 31);
        apix[mi] = valid ? pp : 192;  // 192 = zero row -> padding contributes 0
      }
#pragma unroll
      for (int k2 = 0; k2 < 2; ++k2) {
        const int sl = (k2 << 2) | q;
        bf16x8 af[4];
#pragma unroll
        for (int mi = 0; mi < 4; ++mi)
          af[mi] = *(const bf16x8*)(ldsAc + apix[mi] * 128 + ((sl ^ (apix[mi] & 7)) << 4));
#pragma unroll
        for (int ni = 0; ni < 4; ++ni) {
          const bf16x8 bfr = *(const bf16x8*)(ldsBc + coL[ni] * 128 + ((sl ^ (coL[ni] & 7)) << 4));
#pragma unroll
          for (int mi = 0; mi < 4; ++mi)
            acc[mi][ni] = __builtin_amdgcn_mfma_f32_16x16x32_bf16(af[mi], bfr, acc[mi][ni], 0, 0, 0);
        }
      }
    }
  }

  const float alpha = alphas[aidx];
  if constexpr (EPI == 0) {
    // h = alpha*S; a2 = sign(h*inv2 + add2) as bf16 bits, NHWC
#pragma unroll
    for (int ni = 0; ni < 4; ++ni) {
      const int co = wbase + coL[ni];
      const float inv = inv2[co];
      const float ad = add2[co];
#pragma unroll
      for (int mi = 0; mi < 4; ++mi) {
        const int prow = mb * 128 + wm * 64 + mi * 16 + (q << 2);
#pragma unroll
        for (int j = 0; j < 4; ++j) {
          const float h = alpha * acc[mi][ni][j];
          const float tt = fmaf(h, inv, ad);
          aout[(prow + j) * 256 + co] = (tt >= 0.f) ? (uint16_t)0x3F80u : (uint16_t)0xBF80u;
        }
      }
    }
  } else {
    // out = x + alpha*S, NCHW float4 stores
#pragma unroll
    for (int ni = 0; ni < 4; ++ni) {
      const int co = wbase + coL[ni];
#pragma unroll
      for (int mi = 0; mi < 4; ++mi) {
        const int pimg = ((mb & 7) << 7) + wm * 64 + mi * 16 + (q << 2);
        const int off = (((n << 8) + co) << 10) + pimg;
        const float4 xv = *(const float4*)(xres + off);
        float4 o;
        o.x = xv.x + alpha * acc[mi][ni][0];
        o.y = xv.y + alpha * acc[mi][ni][1];
        o.z = xv.z + alpha * acc[mi][ni][2];
        o.w = xv.w + alpha * acc[mi][ni][3];
        *(float4*)(fout + off) = o;
      }
    }
  }
}

extern "C" void kernel_launch(void* const* d_in, const int* in_sizes, int n_in,
                              void* d_out, int out_size, void* d_ws, size_t ws_size,
                              hipStream_t stream) {
  const float* x  = (const float*)d_in[0];
  const float* g1 = (const float*)d_in[1];
  const float* b1 = (const float*)d_in[2];
  const float* m1 = (const float*)d_in[3];
  const float* v1 = (const float*)d_in[4];
  const float* w1 = (const float*)d_in[5];
  const float* g2 = (const float*)d_in[6];
  const float* b2 = (const float*)d_in[7];
  const float* m2 = (const float*)d_in[8];
  const float* v2 = (const float*)d_in[9];
  const float* w2 = (const float*)d_in[10];
  float* out = (float*)d_out;

  char* ws = (char*)d_ws;
  uint16_t* a1   = (uint16_t*)(ws);
  uint16_t* a2   = (uint16_t*)(ws + 33554432);
  uint16_t* wqt1 = (uint16_t*)(ws + 67108864);
  uint16_t* wqt2 = (uint16_t*)(ws + 67108864 + 1179648);
  float* fs = (float*)(ws + 67108864 + 2359296);
  float* pd1    = fs;
  float* pd2    = fs + 128;
  float* deltas = fs + 256;
  float* alphas = fs + 260;
  float* ps1    = fs + 512;
  float* pc1    = fs + 512 + 2304;
  float* ps2    = fs + 512 + 4608;
  float* pc2    = fs + 512 + 6912;
  float* inv2   = fs + 512 + 9216;
  float* add2   = fs + 512 + 9472;

  hipLaunchKernelGGL(wsum_kernel, dim3(72), dim3(256), 0, stream, w1, pd1);
  hipLaunchKernelGGL(wsum_kernel, dim3(72), dim3(256), 0, stream, w2, pd2);
  hipLaunchKernelGGL(delta_kernel, dim3(1), dim3(64), 0, stream, pd1, pd2, deltas);
  hipLaunchKernelGGL(quant_kernel, dim3(2304), dim3(256), 0, stream, w1, deltas, 0, wqt1, ps1, pc1);
  hipLaunchKernelGGL(quant_kernel, dim3(2304), dim3(256), 0, stream, w2, deltas, 1, wqt2, ps2, pc2);
  hipLaunchKernelGGL(alpha_kernel, dim3(1), dim3(256), 0, stream,
                     ps1, pc1, ps2, pc2, g2, b2, m2, v2, alphas, inv2, add2);
  hipLaunchKernelGGL(bn_bin_kernel, dim3(16, 8, 64), dim3(256), 0, stream, x, g1, b1, m1, v1, a1);
  hipLaunchKernelGGL((conv3x3_tbn<0>), dim3(1024), dim3(256), 0, stream,
                     a1, wqt1, alphas, 0, inv2, add2, (const float*)nullptr,
                     a2, (float*)nullptr);
  hipLaunchKernelGGL((conv3x3_tbn<1>), dim3(1024), dim3(256), 0, stream,
                     a2, wqt2, alphas, 1, (const float*)nullptr, (const float*)nullptr, x,
                     (uint16_t*)nullptr, out);
  (void)in_sizes; (void)n_in; (void)out_size; (void)ws_size;
}

// Round 2
// 270.125 us; speedup vs baseline: 2.2226x; 2.2226x over previous
//
#include <hip/hip_runtime.h>
#include <stdint.h>

// TBN BasicBlock on MI355X:
//   out = x + conv3x3(sign(bn2(conv3x3(sign(bn1(x)), tern(w1)))), tern(w2))
// Binary acts (+-1) and ternary weights ({-1,0,+1}, alpha factored out) are
// exact in bf16, so both convs run as implicit-GEMM bf16 MFMA with fp32
// accumulation (integer-exact), alpha applied in the epilogue.
//
// Round 2: conv restructured to pipelined global_load_lds staging:
//  - B tiles double-buffered, staged with global_load_lds (linear dest,
//    swizzle baked into the wqt global layout by quant_kernel)
//  - A tile staged once per ci-chunk, swizzle baked into per-lane source addr
//  - ONE barrier per tap-step (prefetch issued before MFMA, drained by the
//    barrier's implicit vmcnt(0)); extra drain only at 3 chunk boundaries
//  - XCD-aware block swizzle so nb-pairs (sharing A rows) share an L2

#define EPS 1e-5f

typedef __bf16 bf16x8 __attribute__((ext_vector_type(8)));
typedef float  f32x4  __attribute__((ext_vector_type(4)));

__device__ __forceinline__ void gload16(const uint16_t* g, uint16_t* l) {
  __builtin_amdgcn_global_load_lds(
      (const __attribute__((address_space(1))) void*)g,
      (__attribute__((address_space(3))) void*)l, 16, 0, 0);
}

// ---------------- stage 1: sum |w| (deterministic 2-level reduction) --------
__global__ __launch_bounds__(256) void wsum_kernel(const float* __restrict__ w,
                                                   float* __restrict__ partial) {
  __shared__ float red[256];
  const int t = threadIdx.x;
  const int b = blockIdx.x;
  float s = 0.f;
#pragma unroll
  for (int i = 0; i < 32; ++i) s += fabsf(w[b * 256 + t + i * 18432]);
  red[t] = s;
  __syncthreads();
  for (int o = 128; o > 0; o >>= 1) {
    if (t < o) red[t] += red[t + o];
    __syncthreads();
  }
  if (t == 0) partial[b] = red[0];
}

__global__ void delta_kernel(const float* __restrict__ p1, const float* __restrict__ p2,
                             float* __restrict__ delta) {
  const int t = threadIdx.x;
  if (t < 2) {
    const float* p = (t == 0) ? p1 : p2;
    double s = 0.0;
    for (int i = 0; i < 72; ++i) s += (double)p[i];
    delta[t] = 0.7f * (float)(s * (1.0 / 589824.0));
  }
}

// ------------- stage 2: quantize + transpose weights, alpha partials --------
// Output layout is PRE-SWIZZLED for linear global_load_lds staging:
//   elem (co, ci, tap): chunk=ci>>6, slot=(ci&63)>>3, w=ci&7
//   dest = ((chunk*9+tap)*256 + co)*64 + (slot ^ (co&7))*8 + w
__global__ __launch_bounds__(256) void quant_kernel(const float* __restrict__ w,
                                                    const float* __restrict__ delta2, const int didx,
                                                    uint16_t* __restrict__ wqt,
                                                    float* __restrict__ psum,
                                                    float* __restrict__ pcnt) {
  __shared__ float rs[256];
  __shared__ float rc[256];
  const int t = threadIdx.x;
  const int idx = blockIdx.x * 256 + t;
  const float d = delta2[didx];
  const float v = w[idx];
  const float av = fabsf(v);
  const bool m = av > d;
  const int co = idx / 2304;
  const int rem = idx - co * 2304;
  const int ci = rem / 9;
  const int tap = rem - ci * 9;
  const int chunk = ci >> 6;
  const int cil = ci & 63;
  const int slot = cil >> 3;
  const int ww = cil & 7;
  const int slot_s = slot ^ (co & 7);
  wqt[((chunk * 9 + tap) * 256 + co) * 64 + slot_s * 8 + ww] =
      m ? (v > 0.f ? (uint16_t)0x3F80u : (uint16_t)0xBF80u) : (uint16_t)0u;
  rs[t] = m ? av : 0.f;
  rc[t] = m ? 1.f : 0.f;
  __syncthreads();
  for (int o = 128; o > 0; o >>= 1) {
    if (t < o) { rs[t] += rs[t + o]; rc[t] += rc[t + o]; }
    __syncthreads();
  }
  if (t == 0) { psum[blockIdx.x] = rs[0]; pcnt[blockIdx.x] = rc[0]; }
}

__global__ __launch_bounds__(256) void alpha_kernel(const float* __restrict__ ps1, const float* __restrict__ pc1,
                                                    const float* __restrict__ ps2, const float* __restrict__ pc2,
                                                    const float* __restrict__ g2, const float* __restrict__ b2,
                                                    const float* __restrict__ m2, const float* __restrict__ v2,
                                                    float* __restrict__ alphas,
                                                    float* __restrict__ inv2o, float* __restrict__ add2o) {
  __shared__ float rs[256];
  __shared__ float rc[256];
  const int t = threadIdx.x;
  float s1 = 0.f, c1 = 0.f, s2 = 0.f, c2 = 0.f;
#pragma unroll
  for (int i = 0; i < 9; ++i) {
    s1 += ps1[t + (i << 8)]; c1 += pc1[t + (i << 8)];
    s2 += ps2[t + (i << 8)]; c2 += pc2[t + (i << 8)];
  }
  rs[t] = s1; rc[t] = c1;
  __syncthreads();
  for (int o = 128; o > 0; o >>= 1) {
    if (t < o) { rs[t] += rs[t + o]; rc[t] += rc[t + o]; }
    __syncthreads();
  }
  if (t == 0) alphas[0] = rs[0] / fmaxf(rc[0], 1.f);
  __syncthreads();
  rs[t] = s2; rc[t] = c2;
  __syncthreads();
  for (int o = 128; o > 0; o >>= 1) {
    if (t < o) { rs[t] += rs[t + o]; rc[t] += rc[t + o]; }
    __syncthreads();
  }
  if (t == 0) alphas[1] = rs[0] / fmaxf(rc[0], 1.f);
  const float inv = g2[t] * rsqrtf(v2[t] + EPS);
  inv2o[t] = inv;
  add2o[t] = b2[t] - m2[t] * inv;
}

// -------- stage 3: bn1 + binarize + NCHW -> NHWC (bf16 +-1 bits) ------------
__global__ __launch_bounds__(256) void bn_bin_kernel(const float* __restrict__ x,
                                                     const float* __restrict__ g1,
                                                     const float* __restrict__ b1,
                                                     const float* __restrict__ m1,
                                                     const float* __restrict__ v1,
                                                     uint16_t* __restrict__ a1) {
  __shared__ uint16_t lds[64 * 36];
  const int t = threadIdx.x;
  const int p0 = blockIdx.x << 6;
  const int c0 = blockIdx.y << 5;
  const int n = blockIdx.z;
  const int pl = t & 63;
  const int cl0 = t >> 6;
#pragma unroll
  for (int i = 0; i < 8; ++i) {
    const int cl = cl0 + (i << 2);
    const int c = c0 + cl;
    const float inv = g1[c] * rsqrtf(v1[c] + EPS);
    const float ad = b1[c] - m1[c] * inv;
    const float val = x[(((n << 8) + c) << 10) + p0 + pl];
    const float tt = fmaf(val, inv, ad);
    lds[pl * 36 + cl] = (tt >= 0.f) ? (uint16_t)0x3F80u : (uint16_t)0xBF80u;
  }
  __syncthreads();
  const int pl2 = t >> 2;
  const int s2 = (t & 3) << 3;
  const uint2 lo = *(const uint2*)&lds[pl2 * 36 + s2];
  const uint2 hi = *(const uint2*)&lds[pl2 * 36 + s2 + 4];
  uint4 o; o.x = lo.x; o.y = lo.y; o.z = hi.x; o.w = hi.y;
  *(uint4*)&a1[(((n << 10) + p0 + pl2) << 8) + c0 + s2] = o;
}

// -------- stages 4/5: pipelined implicit-GEMM conv3x3 -----------------------
// BM=128 pixels (4 image rows) x BN=128 cout, 4 waves (2M x 2N).
// K-loop: 4 ci-chunks of 64 x 9 taps = 36 steps of K=64.
// A staged once per chunk (6 image rows incl. halo, 192 LDS rows + zero row),
// B double-buffered, one barrier/step, global_load_lds everywhere.
template <int EPI>
__global__ __launch_bounds__(256) void conv3x3_tbn(
    const uint16_t* __restrict__ act,   // NHWC bf16-bits [B*1024][256]
    const uint16_t* __restrict__ wswz,  // pre-swizzled [panel36][co256][64]
    const float* __restrict__ alphas, const int aidx,
    const float* __restrict__ inv2, const float* __restrict__ add2,  // EPI==0
    const float* __restrict__ xres,                                  // EPI==1
    uint16_t* __restrict__ aout, float* __restrict__ fout) {
  __shared__ uint16_t ldsA[193 * 64];      // 192 rows x 128B + zero row (24704 B)
  __shared__ uint16_t ldsB[2 * 128 * 64];  // 2 x 16 KB double buffer
  const char* ldsAc = (const char*)ldsA;
  const char* ldsBc = (const char*)ldsB;

  const int tid = threadIdx.x;
  // XCD-aware swizzle: grid=1024 (%8==0); logical id groups 128 consecutive
  // blocks per XCD so nb-pairs + neighboring pixel tiles share an L2.
  const int bid = blockIdx.x;
  const int L = (bid & 7) * 128 + (bid >> 3);
  const int mb = L >> 1;            // 512 pixel tiles
  const int nb = L & 1;             // 2 cout halves
  const int n = mb >> 3;
  const int y0 = (mb & 7) << 2;     // 4 image rows per tile
  const int l = tid & 63;
  const int wid = tid >> 6;
  const int wm = wid >> 1;
  const int wn = wid & 1;
  const int q = l >> 4;
  const int r = l & 15;

  int ylocal[4], xcol[4];
  int bBase[4], bXor[4];
#pragma unroll
  for (int mi = 0; mi < 4; ++mi) {
    const int p = wm * 64 + mi * 16 + r;
    ylocal[mi] = p >> 5;
    xcol[mi] = p & 31;
  }
#pragma unroll
  for (int ni = 0; ni < 4; ++ni) {
    const int co = wn * 64 + ni * 16 + r;
    bBase[ni] = co * 128;
    bXor[ni] = (co & 7) << 4;
  }

  // A staging source offsets (elements), swizzle baked into source slot
  int aSrcOff[6];
#pragma unroll
  for (int i = 0; i < 6; ++i) {
    const int idx = tid + (i << 8);
    const int pix = idx >> 3, ss = idx & 7;
    int ys = y0 - 1 + (pix >> 5);
    ys = ys < 0 ? 0 : (ys > 31 ? 31 : ys);  // clamp (OOB rows never read)
    aSrcOff[i] = (((n << 10) + (ys << 5) + (pix & 31)) << 8) + ((ss ^ (pix & 7)) << 3);
  }

  if (tid < 8) *(uint4*)((char*)ldsA + 192 * 128 + tid * 16) = make_uint4(0u, 0u, 0u, 0u);

  const f32x4 fz = {0.f, 0.f, 0.f, 0.f};
  f32x4 acc[4][4];
#pragma unroll
  for (int mi = 0; mi < 4; ++mi)
#pragma unroll
    for (int ni = 0; ni < 4; ++ni) acc[mi][ni] = fz;

  const int bThr = tid << 3;  // element offset within a panel half

  // prologue: stage A chunk 0 + B panel 0 into buf 0
#pragma unroll
  for (int i = 0; i < 6; ++i)
    gload16(act + aSrcOff[i], (uint16_t*)((char*)ldsA + tid * 16 + i * 4096));
#pragma unroll
  for (int i = 0; i < 4; ++i)
    gload16(wswz + (nb << 13) + bThr + (i << 11),
            (uint16_t*)((char*)ldsB + tid * 16 + i * 4096));
  __syncthreads();  // implicit vmcnt(0) drain

  int buf = 0;
  for (int chunk = 0; chunk < 4; ++chunk) {
#pragma unroll
    for (int tap = 0; tap < 9; ++tap) {
      const int ky = tap / 3, kx = tap % 3;
      const int stp = chunk * 9 + tap;
      // ---- prefetch next B panel into other buffer (overlaps MFMA) ----
      if (stp < 35) {
        const int pn = (stp + 1) << 14;  // panel elem offset = (stp+1)*16384
#pragma unroll
        for (int i = 0; i < 4; ++i)
          gload16(wswz + pn + (nb << 13) + bThr + (i << 11),
                  (uint16_t*)((char*)ldsB + ((buf ^ 1) << 14) + tid * 16 + i * 4096));
      }
      // ---- compute from current buffers ----
      int pBase[4], pXor[4];
#pragma unroll
      for (int mi = 0; mi < 4; ++mi) {
        const int xs = xcol[mi] + kx - 1;
        const int ys = y0 + ylocal[mi] + ky - 1;
        const bool valid = ((unsigned)xs < 32u) && ((unsigned)ys < 32u);
        const int pp = ((ylocal[mi] + ky) << 5) + (xs & 31);
        const int apix = valid ? pp : 192;  // zero row for halo
        pBase[mi] = apix << 7;
        pXor[mi] = (apix & 7) << 4;
      }
      const int bufo = buf << 14;
#pragma unroll
      for (int k2 = 0; k2 < 2; ++k2) {
        const int slb = (((k2 << 2) | q) << 4);
        bf16x8 af[4];
#pragma unroll
        for (int mi = 0; mi < 4; ++mi)
          af[mi] = *(const bf16x8*)(ldsAc + pBase[mi] + (slb ^ pXor[mi]));
#pragma unroll
        for (int ni = 0; ni < 4; ++ni) {
          const bf16x8 bfr = *(const bf16x8*)(ldsBc + bufo + bBase[ni] + (slb ^ bXor[ni]));
#pragma unroll
          for (int mi = 0; mi < 4; ++mi)
            acc[mi][ni] = __builtin_amdgcn_mfma_f32_16x16x32_bf16(af[mi], bfr, acc[mi][ni], 0, 0, 0);
        }
      }
      // ---- single barrier per step (drains B prefetch via vmcnt(0)) ----
      if (stp < 35) {
        __syncthreads();
        if (tap == 8) {  // chunk boundary: restage A
#pragma unroll
          for (int i = 0; i < 6; ++i)
            gload16(act + aSrcOff[i] + ((chunk + 1) << 6),
                    (uint16_t*)((char*)ldsA + tid * 16 + i * 4096));
          __syncthreads();
        }
      }
      buf ^= 1;
    }
  }

  const float alpha = alphas[aidx];
  const int wbase = nb << 7;
  if constexpr (EPI == 0) {
#pragma unroll
    for (int ni = 0; ni < 4; ++ni) {
      const int co = wbase + wn * 64 + ni * 16 + r;
      const float inv = inv2[co];
      const float ad = add2[co];
#pragma unroll
      for (int mi = 0; mi < 4; ++mi) {
        const int prow = mb * 128 + wm * 64 + mi * 16 + (q << 2);
#pragma unroll
        for (int j = 0; j < 4; ++j) {
          const float h = alpha * acc[mi][ni][j];
          const float tt = fmaf(h, inv, ad);
          aout[(prow + j) * 256 + co] = (tt >= 0.f) ? (uint16_t)0x3F80u : (uint16_t)0xBF80u;
        }
      }
    }
  } else {
#pragma unroll
    for (int ni = 0; ni < 4; ++ni) {
      const int co = wbase + wn * 64 + ni * 16 + r;
#pragma unroll
      for (int mi = 0; mi < 4; ++mi) {
        const int pimg = ((mb & 7) << 7) + wm * 64 + mi * 16 + (q << 2);
        const int off = (((n << 8) + co) << 10) + pimg;
        const float4 xv = *(const float4*)(xres + off);
        float4 o;
        o.x = xv.x + alpha * acc[mi][ni][0];
        o.y = xv.y + alpha * acc[mi][ni][1];
        o.z = xv.z + alpha * acc[mi][ni][2];
        o.w = xv.w + alpha * acc[mi][ni][3];
        *(float4*)(fout + off) = o;
      }
    }
  }
}

extern "C" void kernel_launch(void* const* d_in, const int* in_sizes, int n_in,
                              void* d_out, int out_size, void* d_ws, size_t ws_size,
                              hipStream_t stream) {
  const float* x  = (const float*)d_in[0];
  const float* g1 = (const float*)d_in[1];
  const float* b1 = (const float*)d_in[2];
  const float* m1 = (const float*)d_in[3];
  const float* v1 = (const float*)d_in[4];
  const float* w1 = (const float*)d_in[5];
  const float* g2 = (const float*)d_in[6];
  const float* b2 = (const float*)d_in[7];
  const float* m2 = (const float*)d_in[8];
  const float* v2 = (const float*)d_in[9];
  const float* w2 = (const float*)d_in[10];
  float* out = (float*)d_out;

  char* ws = (char*)d_ws;
  uint16_t* a1   = (uint16_t*)(ws);
  uint16_t* a2   = (uint16_t*)(ws + 33554432);
  uint16_t* wqt1 = (uint16_t*)(ws + 67108864);
  uint16_t* wqt2 = (uint16_t*)(ws + 67108864 + 1179648);
  float* fs = (float*)(ws + 67108864 + 2359296);
  float* pd1    = fs;
  float* pd2    = fs + 128;
  float* deltas = fs + 256;
  float* alphas = fs + 260;
  float* ps1    = fs + 512;
  float* pc1    = fs + 512 + 2304;
  float* ps2    = fs + 512 + 4608;
  float* pc2    = fs + 512 + 6912;
  float* inv2   = fs + 512 + 9216;
  float* add2   = fs + 512 + 9472;

  hipLaunchKernelGGL(wsum_kernel, dim3(72), dim3(256), 0, stream, w1, pd1);
  hipLaunchKernelGGL(wsum_kernel, dim3(72), dim3(256), 0, stream, w2, pd2);
  hipLaunchKernelGGL(delta_kernel, dim3(1), dim3(64), 0, stream, pd1, pd2, deltas);
  hipLaunchKernelGGL(quant_kernel, dim3(2304), dim3(256), 0, stream, w1, deltas, 0, wqt1, ps1, pc1);
  hipLaunchKernelGGL(quant_kernel, dim3(2304), dim3(256), 0, stream, w2, deltas, 1, wqt2, ps2, pc2);
  hipLaunchKernelGGL(alpha_kernel, dim3(1), dim3(256), 0, stream,
                     ps1, pc1, ps2, pc2, g2, b2, m2, v2, alphas, inv2, add2);
  hipLaunchKernelGGL(bn_bin_kernel, dim3(16, 8, 64), dim3(256), 0, stream, x, g1, b1, m1, v1, a1);
  hipLaunchKernelGGL((conv3x3_tbn<0>), dim3(1024), dim3(256), 0, stream,
                     a1, wqt1, alphas, 0, inv2, add2, (const float*)nullptr,
                     a2, (float*)nullptr);
  hipLaunchKernelGGL((conv3x3_tbn<1>), dim3(1024), dim3(256), 0, stream,
                     a2, wqt2, alphas, 1, (const float*)nullptr, (const float*)nullptr, x,
                     (uint16_t*)nullptr, out);
  (void)in_sizes; (void)n_in; (void)out_size; (void)ws_size;
}

// Round 3
// 141.928 us; speedup vs baseline: 4.2301x; 1.9033x over previous
//
#include <hip/hip_runtime.h>
#include <stdint.h>

// TBN BasicBlock on MI355X, round 3: int8 datapath.
//   out = x + conv3x3(sign(bn2(conv3x3(sign(bn1(x)), tern(w1)))), tern(w2))
// +-1 activations and {-1,0,+1} weights (alpha factored out) as int8,
// mfma_i32_16x16x64_i8 with i32 accumulation -> exact.
// Conv structure: BM=256 pixels x BN=128 cout per block, 4 waves (2Mx2N),
// wave tile 128x64 (mi=8, ni=4). K-loop = 4 ci-chunks of 64; per chunk ALL
// nine 3x3-tap B panels are LDS-resident (72KB) + A rows incl. halo (21KB),
// so the 9-tap compute runs with no barriers inside. 7 barriers total.

#define EPS 1e-5f

typedef int i32x4 __attribute__((ext_vector_type(4)));

__device__ __forceinline__ void gload16(const void* g, void* l) {
  __builtin_amdgcn_global_load_lds(
      (const __attribute__((address_space(1))) void*)g,
      (__attribute__((address_space(3))) void*)l, 16, 0, 0);
}

// ---------------- stage 1: sum |w| (deterministic 2-level reduction) --------
__global__ __launch_bounds__(256) void wsum_kernel(const float* __restrict__ w,
                                                   float* __restrict__ partial) {
  __shared__ float red[256];
  const int t = threadIdx.x;
  const int b = blockIdx.x;
  float s = 0.f;
#pragma unroll
  for (int i = 0; i < 32; ++i) s += fabsf(w[b * 256 + t + i * 18432]);
  red[t] = s;
  __syncthreads();
  for (int o = 128; o > 0; o >>= 1) {
    if (t < o) red[t] += red[t + o];
    __syncthreads();
  }
  if (t == 0) partial[b] = red[0];
}

__global__ void delta_kernel(const float* __restrict__ p1, const float* __restrict__ p2,
                             float* __restrict__ delta) {
  const int t = threadIdx.x;
  if (t < 2) {
    const float* p = (t == 0) ? p1 : p2;
    double s = 0.0;
    for (int i = 0; i < 72; ++i) s += (double)p[i];
    delta[t] = 0.7f * (float)(s * (1.0 / 589824.0));
  }
}

// ------------- stage 2: quantize + transpose weights, alpha partials --------
// Weight global layout == the LDS layout the conv stages linearly:
//   panel p = (ci>>6)*9 + tap  (36 panels of 16KB)
//   within panel: [cohalf 2][slot 4][co 128][byte 16]
//   where cil=ci&63, slot=cil>>4, b=cil&15
__global__ __launch_bounds__(256) void quant_kernel(const float* __restrict__ w,
                                                    const float* __restrict__ delta2, const int didx,
                                                    int8_t* __restrict__ wq,
                                                    float* __restrict__ psum,
                                                    float* __restrict__ pcnt) {
  __shared__ float rs[256];
  __shared__ float rc[256];
  const int t = threadIdx.x;
  const int idx = blockIdx.x * 256 + t;
  const float d = delta2[didx];
  const float v = w[idx];
  const float av = fabsf(v);
  const bool m = av > d;
  const int co = idx / 2304;
  const int rem = idx - co * 2304;
  const int ci = rem / 9;
  const int tap = rem - ci * 9;
  const int panel = (ci >> 6) * 9 + tap;
  const int cil = ci & 63;
  const int slot = cil >> 4;
  const int b = cil & 15;
  wq[panel * 16384 + (co >> 7) * 8192 + slot * 2048 + (co & 127) * 16 + b] =
      m ? (v > 0.f ? (int8_t)1 : (int8_t)-1) : (int8_t)0;
  rs[t] = m ? av : 0.f;
  rc[t] = m ? 1.f : 0.f;
  __syncthreads();
  for (int o = 128; o > 0; o >>= 1) {
    if (t < o) { rs[t] += rs[t + o]; rc[t] += rc[t + o]; }
    __syncthreads();
  }
  if (t == 0) { psum[blockIdx.x] = rs[0]; pcnt[blockIdx.x] = rc[0]; }
}

__global__ __launch_bounds__(256) void alpha_kernel(const float* __restrict__ ps1, const float* __restrict__ pc1,
                                                    const float* __restrict__ ps2, const float* __restrict__ pc2,
                                                    const float* __restrict__ g2, const float* __restrict__ b2,
                                                    const float* __restrict__ m2, const float* __restrict__ v2,
                                                    float* __restrict__ alphas,
                                                    float* __restrict__ inv2o, float* __restrict__ add2o) {
  __shared__ float rs[256];
  __shared__ float rc[256];
  const int t = threadIdx.x;
  float s1 = 0.f, c1 = 0.f, s2 = 0.f, c2 = 0.f;
#pragma unroll
  for (int i = 0; i < 9; ++i) {
    s1 += ps1[t + (i << 8)]; c1 += pc1[t + (i << 8)];
    s2 += ps2[t + (i << 8)]; c2 += pc2[t + (i << 8)];
  }
  rs[t] = s1; rc[t] = c1;
  __syncthreads();
  for (int o = 128; o > 0; o >>= 1) {
    if (t < o) { rs[t] += rs[t + o]; rc[t] += rc[t + o]; }
    __syncthreads();
  }
  if (t == 0) alphas[0] = rs[0] / fmaxf(rc[0], 1.f);
  __syncthreads();
  rs[t] = s2; rc[t] = c2;
  __syncthreads();
  for (int o = 128; o > 0; o >>= 1) {
    if (t < o) { rs[t] += rs[t + o]; rc[t] += rc[t + o]; }
    __syncthreads();
  }
  if (t == 0) alphas[1] = rs[0] / fmaxf(rc[0], 1.f);
  const float inv = g2[t] * rsqrtf(v2[t] + EPS);
  inv2o[t] = inv;
  add2o[t] = b2[t] - m2[t] * inv;
}

// -------- stage 3: bn1 + binarize + NCHW -> NHWC (+-1 int8) -----------------
__global__ __launch_bounds__(256) void bn_bin_kernel(const float* __restrict__ x,
                                                     const float* __restrict__ g1,
                                                     const float* __restrict__ b1,
                                                     const float* __restrict__ m1,
                                                     const float* __restrict__ v1,
                                                     int8_t* __restrict__ a1) {
  __shared__ int8_t lds[64 * 40];  // [pixel][channel], stride 40 (8-aligned reads)
  const int t = threadIdx.x;
  const int p0 = blockIdx.x << 6;
  const int c0 = blockIdx.y << 5;
  const int n = blockIdx.z;
  const int pl = t & 63;
  const int cl0 = t >> 6;
#pragma unroll
  for (int i = 0; i < 8; ++i) {
    const int cl = cl0 + (i << 2);
    const int c = c0 + cl;
    const float inv = g1[c] * rsqrtf(v1[c] + EPS);
    const float ad = b1[c] - m1[c] * inv;
    const float val = x[(((n << 8) + c) << 10) + p0 + pl];
    const float tt = fmaf(val, inv, ad);
    lds[pl * 40 + cl] = (tt >= 0.f) ? (int8_t)1 : (int8_t)-1;
  }
  __syncthreads();
  const int pl2 = t >> 2;
  const int s2 = (t & 3) << 3;
  const uint2 o = *(const uint2*)&lds[pl2 * 40 + s2];
  *(uint2*)&a1[(((n << 10) + p0 + pl2) << 8) + c0 + s2] = o;
}

// -------- stages 4/5: per-chunk implicit-GEMM conv3x3 (int8 MFMA) -----------
template <int EPI>
__global__ __launch_bounds__(256) void conv3x3_tbn(
    const int8_t* __restrict__ act,   // NHWC int8 [B*1024][256]
    const int8_t* __restrict__ wq,    // [panel36][half2][slot4][co128][16]
    const float* __restrict__ alphas, const int aidx,
    const float* __restrict__ inv2, const float* __restrict__ add2,  // EPI==0
    const float* __restrict__ xres,                                  // EPI==1
    int8_t* __restrict__ aout, float* __restrict__ fout) {
  __shared__ int8_t ldsA[4 * 336 * 16];      // [slot][pix 336][16B]; 21504 B
  __shared__ int8_t ldsB[9 * 4 * 128 * 16];  // [tap][slot][co][16B]; 73728 B

  const int tid = threadIdx.x;
  const int bid = blockIdx.x;
  const int L = (bid & 7) * 64 + (bid >> 3);  // XCD swizzle, 512 blocks
  const int mb = L >> 1;            // 256 pixel tiles (8 image rows each)
  const int nb = L & 1;             // cout half
  const int n = mb >> 2;
  const int y0 = (mb & 3) << 3;
  const int l = tid & 63;
  const int wid = tid >> 6;
  const int wm = wid >> 1;
  const int wn = wid & 1;
  const int q = l >> 4;
  const int r = l & 15;

  // ---- A staging plan: 1280 dest slots = [slot 4][pix 320], 16B each.
  // Slot boundaries (320 = 5*64) are wave-aligned -> per-wave-linear dest.
  int srcA[5], dstA[5];
#pragma unroll
  for (int i = 0; i < 5; ++i) {
    const int idx = tid + (i << 8);
    const int asl = idx / 320;
    const int apx = idx - asl * 320;
    int ys = y0 - 1 + (apx >> 5);
    ys = ys < 0 ? 0 : (ys > 31 ? 31 : ys);  // clamp (halo rows zeroed via redirect)
    srcA[i] = (((n << 10) + (ys << 5) + (apx & 31)) << 8) + (asl << 4);
    dstA[i] = asl * 5376 + (apx << 4);
  }
  // zero pixel (index 320) in every slot region — never overwritten
  if (tid < 4) *(i32x4*)(ldsA + tid * 5376 + 320 * 16) = (i32x4){0, 0, 0, 0};

  int ylocal[8], xcol[8];
#pragma unroll
  for (int mi = 0; mi < 8; ++mi) {
    const int p = wm * 128 + mi * 16 + r;
    ylocal[mi] = p >> 5;
    xcol[mi] = p & 31;
  }
  int bAddr[4];
#pragma unroll
  for (int ni = 0; ni < 4; ++ni)
    bAddr[ni] = (q << 11) + ((wn * 64 + ni * 16 + r) << 4);

  i32x4 acc[8][4];
#pragma unroll
  for (int mi = 0; mi < 8; ++mi)
#pragma unroll
    for (int ni = 0; ni < 4; ++ni) acc[mi][ni] = (i32x4){0, 0, 0, 0};

  // ---- prologue: stage chunk 0 ----
#pragma unroll
  for (int i = 0; i < 5; ++i) gload16(act + srcA[i], ldsA + dstA[i]);
#pragma unroll
  for (int i = 0; i < 18; ++i)
    gload16(wq + (((i >> 1) << 1) + nb) * 8192 + (((i & 1) << 8) + tid) * 16,
            ldsB + (i << 12) + (tid << 4));
  __syncthreads();  // implicit vmcnt(0): staged data visible

  for (int chunk = 0; chunk < 4; ++chunk) {
    // ---- barrier-free 9-tap compute over resident chunk ----
#pragma unroll
    for (int tap = 0; tap < 9; ++tap) {
      const int ky = tap / 3, kx = tap % 3;
      int aAddr[8];
#pragma unroll
      for (int mi = 0; mi < 8; ++mi) {
        const int xs = xcol[mi] + kx - 1;
        const int ys = y0 + ylocal[mi] + ky - 1;
        const bool valid = ((unsigned)xs < 32u) && ((unsigned)ys < 32u);
        const int apix = valid ? (((ylocal[mi] + ky) << 5) + (xs & 31)) : 320;
        aAddr[mi] = q * 5376 + (apix << 4);
      }
      i32x4 bf[4];
#pragma unroll
      for (int ni = 0; ni < 4; ++ni)
        bf[ni] = *(const i32x4*)(ldsB + (tap << 13) + bAddr[ni]);
#pragma unroll
      for (int mi = 0; mi < 8; ++mi) {
        const i32x4 af = *(const i32x4*)(ldsA + aAddr[mi]);
#pragma unroll
        for (int ni = 0; ni < 4; ++ni)
          acc[mi][ni] = __builtin_amdgcn_mfma_i32_16x16x64_i8(af, bf[ni], acc[mi][ni], 0, 0, 0);
      }
    }
    // ---- restage for next chunk ----
    if (chunk < 3) {
      __syncthreads();  // all waves done reading this chunk
#pragma unroll
      for (int i = 0; i < 5; ++i)
        gload16(act + srcA[i] + ((chunk + 1) << 6), ldsA + dstA[i]);
#pragma unroll
      for (int i = 0; i < 18; ++i)
        gload16(wq + ((((chunk + 1) * 9 + (i >> 1)) << 1) + nb) * 8192 +
                    (((i & 1) << 8) + tid) * 16,
                ldsB + (i << 12) + (tid << 4));
      __syncthreads();  // drain
    }
  }

  const float alpha = alphas[aidx];
  if constexpr (EPI == 0) {
#pragma unroll
    for (int ni = 0; ni < 4; ++ni) {
      const int co = nb * 128 + wn * 64 + ni * 16 + r;
      const float inv = inv2[co];
      const float ad = add2[co];
#pragma unroll
      for (int mi = 0; mi < 8; ++mi) {
        const int prow0 = mb * 256 + wm * 128 + mi * 16 + (q << 2);
#pragma unroll
        for (int j = 0; j < 4; ++j) {
          const float h = alpha * (float)acc[mi][ni][j];
          const float tt = fmaf(h, inv, ad);
          aout[(prow0 + j) * 256 + co] = (tt >= 0.f) ? (int8_t)1 : (int8_t)-1;
        }
      }
    }
  } else {
#pragma unroll
    for (int ni = 0; ni < 4; ++ni) {
      const int co = nb * 128 + wn * 64 + ni * 16 + r;
#pragma unroll
      for (int mi = 0; mi < 8; ++mi) {
        const int pimg = ((mb & 3) << 8) + wm * 128 + mi * 16 + (q << 2);
        const int off = (((n << 8) + co) << 10) + pimg;
        const float4 xv = *(const float4*)(xres + off);
        float4 o;
        o.x = xv.x + alpha * (float)acc[mi][ni][0];
        o.y = xv.y + alpha * (float)acc[mi][ni][1];
        o.z = xv.z + alpha * (float)acc[mi][ni][2];
        o.w = xv.w + alpha * (float)acc[mi][ni][3];
        *(float4*)(fout + off) = o;
      }
    }
  }
}

extern "C" void kernel_launch(void* const* d_in, const int* in_sizes, int n_in,
                              void* d_out, int out_size, void* d_ws, size_t ws_size,
                              hipStream_t stream) {
  const float* x  = (const float*)d_in[0];
  const float* g1 = (const float*)d_in[1];
  const float* b1 = (const float*)d_in[2];
  const float* m1 = (const float*)d_in[3];
  const float* v1 = (const float*)d_in[4];
  const float* w1 = (const float*)d_in[5];
  const float* g2 = (const float*)d_in[6];
  const float* b2 = (const float*)d_in[7];
  const float* m2 = (const float*)d_in[8];
  const float* v2 = (const float*)d_in[9];
  const float* w2 = (const float*)d_in[10];
  float* out = (float*)d_out;

  char* ws = (char*)d_ws;
  int8_t* a1  = (int8_t*)(ws);                       // 16 MB
  int8_t* a2  = (int8_t*)(ws + 16777216);            // 16 MB
  int8_t* wq1 = (int8_t*)(ws + 33554432);            // 576 KB
  int8_t* wq2 = (int8_t*)(ws + 33554432 + 589824);   // 576 KB
  float* fs = (float*)(ws + 33554432 + 1179648);
  float* pd1    = fs;
  float* pd2    = fs + 128;
  float* deltas = fs + 256;
  float* alphas = fs + 260;
  float* ps1    = fs + 512;
  float* pc1    = fs + 512 + 2304;
  float* ps2    = fs + 512 + 4608;
  float* pc2    = fs + 512 + 6912;
  float* inv2   = fs + 512 + 9216;
  float* add2   = fs + 512 + 9472;

  hipLaunchKernelGGL(wsum_kernel, dim3(72), dim3(256), 0, stream, w1, pd1);
  hipLaunchKernelGGL(wsum_kernel, dim3(72), dim3(256), 0, stream, w2, pd2);
  hipLaunchKernelGGL(delta_kernel, dim3(1), dim3(64), 0, stream, pd1, pd2, deltas);
  hipLaunchKernelGGL(quant_kernel, dim3(2304), dim3(256), 0, stream, w1, deltas, 0, wq1, ps1, pc1);
  hipLaunchKernelGGL(quant_kernel, dim3(2304), dim3(256), 0, stream, w2, deltas, 1, wq2, ps2, pc2);
  hipLaunchKernelGGL(alpha_kernel, dim3(1), dim3(256), 0, stream,
                     ps1, pc1, ps2, pc2, g2, b2, m2, v2, alphas, inv2, add2);
  hipLaunchKernelGGL(bn_bin_kernel, dim3(16, 8, 64), dim3(256), 0, stream, x, g1, b1, m1, v1, a1);
  hipLaunchKernelGGL((conv3x3_tbn<0>), dim3(512), dim3(256), 0, stream,
                     a1, wq1, alphas, 0, inv2, add2, (const float*)nullptr,
                     a2, (float*)nullptr);
  hipLaunchKernelGGL((conv3x3_tbn<1>), dim3(512), dim3(256), 0, stream,
                     a2, wq2, alphas, 1, (const float*)nullptr, (const float*)nullptr, x,
                     (int8_t*)nullptr, out);
  (void)in_sizes; (void)n_in; (void)out_size; (void)ws_size;
}

// Round 4
// 131.878 us; speedup vs baseline: 4.5524x; 1.0762x over previous
//
#include <hip/hip_runtime.h>
#include <stdint.h>

// TBN BasicBlock on MI355X, round 4: int8 datapath, 2 blocks/CU.
//   out = x + conv3x3(sign(bn2(conv3x3(sign(bn1(x)), tern(w1)))), tern(w2))
// +-1 activations and {-1,0,+1} weights (alpha factored out) as int8,
// mfma_i32_16x16x64_i8 with i32 accumulation -> exact.
// Conv: BM=256 pixels x BN=64 cout per block, 4 waves (2Mx2N), wave tile
// 128x32 (mi=8, ni=2). K-loop = 4 ci-chunks of 64; per chunk all nine
// 3x3-tap B panels LDS-resident (36.9KB) + A rows incl. halo (21.5KB).
// LDS 58368 B -> 2 blocks/CU (8 waves/CU): the other block's MFMAs cover
// each block's chunk-boundary staging drain. 7 barriers per block total.

#define EPS 1e-5f

typedef int i32x4 __attribute__((ext_vector_type(4)));

__device__ __forceinline__ void gload16(const void* g, void* l) {
  __builtin_amdgcn_global_load_lds(
      (const __attribute__((address_space(1))) void*)g,
      (__attribute__((address_space(3))) void*)l, 16, 0, 0);
}

// ---------------- stage 1: sum |w| (deterministic 2-level reduction) --------
__global__ __launch_bounds__(256) void wsum_kernel(const float* __restrict__ w,
                                                   float* __restrict__ partial) {
  __shared__ float red[256];
  const int t = threadIdx.x;
  const int b = blockIdx.x;
  float s = 0.f;
#pragma unroll
  for (int i = 0; i < 32; ++i) s += fabsf(w[b * 256 + t + i * 18432]);
  red[t] = s;
  __syncthreads();
  for (int o = 128; o > 0; o >>= 1) {
    if (t < o) red[t] += red[t + o];
    __syncthreads();
  }
  if (t == 0) partial[b] = red[0];
}

__global__ void delta_kernel(const float* __restrict__ p1, const float* __restrict__ p2,
                             float* __restrict__ delta) {
  const int t = threadIdx.x;
  if (t < 2) {
    const float* p = (t == 0) ? p1 : p2;
    double s = 0.0;
    for (int i = 0; i < 72; ++i) s += (double)p[i];
    delta[t] = 0.7f * (float)(s * (1.0 / 589824.0));
  }
}

// ------------- stage 2: quantize + transpose weights, alpha partials --------
// Weight global layout == the LDS layout the conv stages linearly:
//   panel p = (ci>>6)*9 + tap  (36 panels of 16KB)
//   within panel: [coq 4][slot 4][co 64][byte 16]
//   where cil=ci&63, slot=cil>>4, b=cil&15, coq=co>>6
__global__ __launch_bounds__(256) void quant_kernel(const float* __restrict__ w,
                                                    const float* __restrict__ delta2, const int didx,
                                                    int8_t* __restrict__ wq,
                                                    float* __restrict__ psum,
                                                    float* __restrict__ pcnt) {
  __shared__ float rs[256];
  __shared__ float rc[256];
  const int t = threadIdx.x;
  const int idx = blockIdx.x * 256 + t;
  const float d = delta2[didx];
  const float v = w[idx];
  const float av = fabsf(v);
  const bool m = av > d;
  const int co = idx / 2304;
  const int rem = idx - co * 2304;
  const int ci = rem / 9;
  const int tap = rem - ci * 9;
  const int panel = (ci >> 6) * 9 + tap;
  const int cil = ci & 63;
  const int slot = cil >> 4;
  const int b = cil & 15;
  wq[panel * 16384 + (co >> 6) * 4096 + slot * 1024 + (co & 63) * 16 + b] =
      m ? (v > 0.f ? (int8_t)1 : (int8_t)-1) : (int8_t)0;
  rs[t] = m ? av : 0.f;
  rc[t] = m ? 1.f : 0.f;
  __syncthreads();
  for (int o = 128; o > 0; o >>= 1) {
    if (t < o) { rs[t] += rs[t + o]; rc[t] += rc[t + o]; }
    __syncthreads();
  }
  if (t == 0) { psum[blockIdx.x] = rs[0]; pcnt[blockIdx.x] = rc[0]; }
}

__global__ __launch_bounds__(256) void alpha_kernel(const float* __restrict__ ps1, const float* __restrict__ pc1,
                                                    const float* __restrict__ ps2, const float* __restrict__ pc2,
                                                    const float* __restrict__ g2, const float* __restrict__ b2,
                                                    const float* __restrict__ m2, const float* __restrict__ v2,
                                                    float* __restrict__ alphas,
                                                    float* __restrict__ inv2o, float* __restrict__ add2o) {
  __shared__ float rs[256];
  __shared__ float rc[256];
  const int t = threadIdx.x;
  float s1 = 0.f, c1 = 0.f, s2 = 0.f, c2 = 0.f;
#pragma unroll
  for (int i = 0; i < 9; ++i) {
    s1 += ps1[t + (i << 8)]; c1 += pc1[t + (i << 8)];
    s2 += ps2[t + (i << 8)]; c2 += pc2[t + (i << 8)];
  }
  rs[t] = s1; rc[t] = c1;
  __syncthreads();
  for (int o = 128; o > 0; o >>= 1) {
    if (t < o) { rs[t] += rs[t + o]; rc[t] += rc[t + o]; }
    __syncthreads();
  }
  if (t == 0) alphas[0] = rs[0] / fmaxf(rc[0], 1.f);
  __syncthreads();
  rs[t] = s2; rc[t] = c2;
  __syncthreads();
  for (int o = 128; o > 0; o >>= 1) {
    if (t < o) { rs[t] += rs[t + o]; rc[t] += rc[t + o]; }
    __syncthreads();
  }
  if (t == 0) alphas[1] = rs[0] / fmaxf(rc[0], 1.f);
  const float inv = g2[t] * rsqrtf(v2[t] + EPS);
  inv2o[t] = inv;
  add2o[t] = b2[t] - m2[t] * inv;
}

// -------- stage 3: bn1 + binarize + NCHW -> NHWC (+-1 int8) -----------------
__global__ __launch_bounds__(256) void bn_bin_kernel(const float* __restrict__ x,
                                                     const float* __restrict__ g1,
                                                     const float* __restrict__ b1,
                                                     const float* __restrict__ m1,
                                                     const float* __restrict__ v1,
                                                     int8_t* __restrict__ a1) {
  __shared__ int8_t lds[64 * 40];  // [pixel][channel], stride 40 (8-aligned reads)
  const int t = threadIdx.x;
  const int p0 = blockIdx.x << 6;
  const int c0 = blockIdx.y << 5;
  const int n = blockIdx.z;
  const int pl = t & 63;
  const int cl0 = t >> 6;
#pragma unroll
  for (int i = 0; i < 8; ++i) {
    const int cl = cl0 + (i << 2);
    const int c = c0 + cl;
    const float inv = g1[c] * rsqrtf(v1[c] + EPS);
    const float ad = b1[c] - m1[c] * inv;
    const float val = x[(((n << 8) + c) << 10) + p0 + pl];
    const float tt = fmaf(val, inv, ad);
    lds[pl * 40 + cl] = (tt >= 0.f) ? (int8_t)1 : (int8_t)-1;
  }
  __syncthreads();
  const int pl2 = t >> 2;
  const int s2 = (t & 3) << 3;
  const uint2 o = *(const uint2*)&lds[pl2 * 40 + s2];
  *(uint2*)&a1[(((n << 10) + p0 + pl2) << 8) + c0 + s2] = o;
}

// -------- stages 4/5: per-chunk implicit-GEMM conv3x3 (int8 MFMA) -----------
template <int EPI>
__global__ __launch_bounds__(256) void conv3x3_tbn(
    const int8_t* __restrict__ act,   // NHWC int8 [B*1024][256]
    const int8_t* __restrict__ wq,    // [panel36][coq4][slot4][co64][16]
    const float* __restrict__ alphas, const int aidx,
    const float* __restrict__ inv2, const float* __restrict__ add2,  // EPI==0
    const float* __restrict__ xres,                                  // EPI==1
    int8_t* __restrict__ aout, float* __restrict__ fout) {
  __shared__ int8_t ldsA[4 * 336 * 16];      // [slot][pix 336][16B]; 21504 B
  __shared__ int8_t ldsB[9 * 4 * 64 * 16];   // [tap][slot][co 64][16B]; 36864 B

  const int tid = threadIdx.x;
  const int bid = blockIdx.x;
  const int L = (bid & 7) * 128 + (bid >> 3);  // XCD swizzle, 1024 blocks
  const int mb = L >> 2;            // 256 pixel tiles (8 image rows each)
  const int nb = L & 3;             // cout quarter (64 couts)
  const int n = mb >> 2;
  const int y0 = (mb & 3) << 3;
  const int l = tid & 63;
  const int wid = tid >> 6;
  const int wm = wid >> 1;
  const int wn = wid & 1;
  const int q = l >> 4;
  const int r = l & 15;

  // ---- A staging plan: 1280 dest slots = [slot 4][pix 320], 16B each.
  // Slot boundaries (320 = 5*64) are wave-aligned -> per-wave-linear dest.
  int srcA[5], dstA[5];
#pragma unroll
  for (int i = 0; i < 5; ++i) {
    const int idx = tid + (i << 8);
    const int asl = idx / 320;
    const int apx = idx - asl * 320;
    int ys = y0 - 1 + (apx >> 5);
    ys = ys < 0 ? 0 : (ys > 31 ? 31 : ys);  // clamp (halo rows zeroed via redirect)
    srcA[i] = (((n << 10) + (ys << 5) + (apx & 31)) << 8) + (asl << 4);
    dstA[i] = asl * 5376 + (apx << 4);
  }
  // zero pixel (index 320) in every slot region — never overwritten
  if (tid < 4) *(i32x4*)(ldsA + tid * 5376 + 320 * 16) = (i32x4){0, 0, 0, 0};

  int ylocal[8], xcol[8];
#pragma unroll
  for (int mi = 0; mi < 8; ++mi) {
    const int p = wm * 128 + mi * 16 + r;
    ylocal[mi] = p >> 5;
    xcol[mi] = p & 31;
  }
  int bAddr[2];
#pragma unroll
  for (int ni = 0; ni < 2; ++ni)
    bAddr[ni] = (q << 10) + ((wn * 32 + ni * 16 + r) << 4);

  i32x4 acc[8][2];
#pragma unroll
  for (int mi = 0; mi < 8; ++mi)
#pragma unroll
    for (int ni = 0; ni < 2; ++ni) acc[mi][ni] = (i32x4){0, 0, 0, 0};

  // ---- prologue: stage chunk 0 ----
#pragma unroll
  for (int i = 0; i < 5; ++i) gload16(act + srcA[i], ldsA + dstA[i]);
#pragma unroll
  for (int i = 0; i < 9; ++i)
    gload16(wq + i * 16384 + (nb << 12) + (tid << 4),
            ldsB + (i << 12) + (tid << 4));
  __syncthreads();  // implicit vmcnt(0): staged data visible

  for (int chunk = 0; chunk < 4; ++chunk) {
    // ---- barrier-free 9-tap compute over resident chunk ----
#pragma unroll
    for (int tap = 0; tap < 9; ++tap) {
      const int ky = tap / 3, kx = tap % 3;
      int aAddr[8];
#pragma unroll
      for (int mi = 0; mi < 8; ++mi) {
        const int xs = xcol[mi] + kx - 1;
        const int ys = y0 + ylocal[mi] + ky - 1;
        const bool valid = ((unsigned)xs < 32u) && ((unsigned)ys < 32u);
        const int apix = valid ? (((ylocal[mi] + ky) << 5) + (xs & 31)) : 320;
        aAddr[mi] = q * 5376 + (apix << 4);
      }
      i32x4 bf[2];
#pragma unroll
      for (int ni = 0; ni < 2; ++ni)
        bf[ni] = *(const i32x4*)(ldsB + (tap << 12) + bAddr[ni]);
      __builtin_amdgcn_s_setprio(1);
#pragma unroll
      for (int mi = 0; mi < 8; ++mi) {
        const i32x4 af = *(const i32x4*)(ldsA + aAddr[mi]);
#pragma unroll
        for (int ni = 0; ni < 2; ++ni)
          acc[mi][ni] = __builtin_amdgcn_mfma_i32_16x16x64_i8(af, bf[ni], acc[mi][ni], 0, 0, 0);
      }
      __builtin_amdgcn_s_setprio(0);
    }
    // ---- restage for next chunk ----
    if (chunk < 3) {
      __syncthreads();  // all waves done reading this chunk
#pragma unroll
      for (int i = 0; i < 5; ++i)
        gload16(act + srcA[i] + ((chunk + 1) << 6), ldsA + dstA[i]);
#pragma unroll
      for (int i = 0; i < 9; ++i)
        gload16(wq + ((chunk + 1) * 9 + i) * 16384 + (nb << 12) + (tid << 4),
                ldsB + (i << 12) + (tid << 4));
      __syncthreads();  // drain
    }
  }

  const float alpha = alphas[aidx];
  if constexpr (EPI == 0) {
#pragma unroll
    for (int ni = 0; ni < 2; ++ni) {
      const int co = nb * 64 + wn * 32 + ni * 16 + r;
      const float inv = inv2[co];
      const float ad = add2[co];
#pragma unroll
      for (int mi = 0; mi < 8; ++mi) {
        const int prow0 = mb * 256 + wm * 128 + mi * 16 + (q << 2);
#pragma unroll
        for (int j = 0; j < 4; ++j) {
          const float h = alpha * (float)acc[mi][ni][j];
          const float tt = fmaf(h, inv, ad);
          aout[(prow0 + j) * 256 + co] = (tt >= 0.f) ? (int8_t)1 : (int8_t)-1;
        }
      }
    }
  } else {
#pragma unroll
    for (int ni = 0; ni < 2; ++ni) {
      const int co = nb * 64 + wn * 32 + ni * 16 + r;
#pragma unroll
      for (int mi = 0; mi < 8; ++mi) {
        const int pimg = ((mb & 3) << 8) + wm * 128 + mi * 16 + (q << 2);
        const int off = (((n << 8) + co) << 10) + pimg;
        const float4 xv = *(const float4*)(xres + off);
        float4 o;
        o.x = xv.x + alpha * (float)acc[mi][ni][0];
        o.y = xv.y + alpha * (float)acc[mi][ni][1];
        o.z = xv.z + alpha * (float)acc[mi][ni][2];
        o.w = xv.w + alpha * (float)acc[mi][ni][3];
        *(float4*)(fout + off) = o;
      }
    }
  }
}

extern "C" void kernel_launch(void* const* d_in, const int* in_sizes, int n_in,
                              void* d_out, int out_size, void* d_ws, size_t ws_size,
                              hipStream_t stream) {
  const float* x  = (const float*)d_in[0];
  const float* g1 = (const float*)d_in[1];
  const float* b1 = (const float*)d_in[2];
  const float* m1 = (const float*)d_in[3];
  const float* v1 = (const float*)d_in[4];
  const float* w1 = (const float*)d_in[5];
  const float* g2 = (const float*)d_in[6];
  const float* b2 = (const float*)d_in[7];
  const float* m2 = (const float*)d_in[8];
  const float* v2 = (const float*)d_in[9];
  const float* w2 = (const float*)d_in[10];
  float* out = (float*)d_out;

  char* ws = (char*)d_ws;
  int8_t* a1  = (int8_t*)(ws);                       // 16 MB
  int8_t* a2  = (int8_t*)(ws + 16777216);            // 16 MB
  int8_t* wq1 = (int8_t*)(ws + 33554432);            // 576 KB
  int8_t* wq2 = (int8_t*)(ws + 33554432 + 589824);   // 576 KB
  float* fs = (float*)(ws + 33554432 + 1179648);
  float* pd1    = fs;
  float* pd2    = fs + 128;
  float* deltas = fs + 256;
  float* alphas = fs + 260;
  float* ps1    = fs + 512;
  float* pc1    = fs + 512 + 2304;
  float* ps2    = fs + 512 + 4608;
  float* pc2    = fs + 512 + 6912;
  float* inv2   = fs + 512 + 9216;
  float* add2   = fs + 512 + 9472;

  hipLaunchKernelGGL(wsum_kernel, dim3(72), dim3(256), 0, stream, w1, pd1);
  hipLaunchKernelGGL(wsum_kernel, dim3(72), dim3(256), 0, stream, w2, pd2);
  hipLaunchKernelGGL(delta_kernel, dim3(1), dim3(64), 0, stream, pd1, pd2, deltas);
  hipLaunchKernelGGL(quant_kernel, dim3(2304), dim3(256), 0, stream, w1, deltas, 0, wq1, ps1, pc1);
  hipLaunchKernelGGL(quant_kernel, dim3(2304), dim3(256), 0, stream, w2, deltas, 1, wq2, ps2, pc2);
  hipLaunchKernelGGL(alpha_kernel, dim3(1), dim3(256), 0, stream,
                     ps1, pc1, ps2, pc2, g2, b2, m2, v2, alphas, inv2, add2);
  hipLaunchKernelGGL(bn_bin_kernel, dim3(16, 8, 64), dim3(256), 0, stream, x, g1, b1, m1, v1, a1);
  hipLaunchKernelGGL((conv3x3_tbn<0>), dim3(1024), dim3(256), 0, stream,
                     a1, wq1, alphas, 0, inv2, add2, (const float*)nullptr,
                     a2, (float*)nullptr);
  hipLaunchKernelGGL((conv3x3_tbn<1>), dim3(1024), dim3(256), 0, stream,
                     a2, wq2, alphas, 1, (const float*)nullptr, (const float*)nullptr, x,
                     (int8_t*)nullptr, out);
  (void)in_sizes; (void)n_in; (void)out_size; (void)ws_size;
}